// Round 2
// baseline (429.639 us; speedup 1.0000x reference)
//
#include <hip/hip_runtime.h>
#include <hip/hip_bf16.h>
#include <math.h>

typedef unsigned short u16;
typedef unsigned int u32;

#define Bz 2
#define Sz 2048
#define Dz 2048
#define Hz 16
#define HDz 128
#define Mz 4096

typedef __bf16 bf16x8 __attribute__((ext_vector_type(8)));
typedef float f32x4 __attribute__((ext_vector_type(4)));

__device__ __forceinline__ float bf2f(u16 h) {
    union { u32 u; float f; } x; x.u = ((u32)h) << 16; return x.f;
}
__device__ __forceinline__ u16 f2bf(float f) {
    union { float f; u32 u; } x; x.f = f;
    u32 u = x.u;
    return (u16)((u + 0x7FFFu + ((u >> 16) & 1u)) >> 16);
}

// ---------------- fp32 -> bf16 convert (x) ---------------------------------
__global__ void cvt_f32_bf16(const float* __restrict__ src, u16* __restrict__ dst) {
    size_t i = (size_t)blockIdx.x * blockDim.x + threadIdx.x;  // one per 8 elems
    float4 a = ((const float4*)src)[2 * i];
    float4 b = ((const float4*)src)[2 * i + 1];
    u16 r[8] = {f2bf(a.x), f2bf(a.y), f2bf(a.z), f2bf(a.w),
                f2bf(b.x), f2bf(b.y), f2bf(b.z), f2bf(b.w)};
    *(uint4*)(dst + 8 * i) = *(const uint4*)r;
}

// ---------------- weight transpose+convert: Wt[n][k] = bf16(W[k][n]) -------
__global__ void transpose_w(const float* __restrict__ W0, const float* __restrict__ W1,
                            const float* __restrict__ W2, const float* __restrict__ W3,
                            u16* __restrict__ Wt) {
    __shared__ u16 t[64][65];
    const float* src = (blockIdx.z == 0) ? W0 : (blockIdx.z == 1) ? W1
                     : (blockIdx.z == 2) ? W2 : W3;
    u16* dst = Wt + (size_t)blockIdx.z * (Dz * Dz);
    int x = blockIdx.x * 64, y = blockIdx.y * 64;
    int c = threadIdx.x & 63, rb = (threadIdx.x >> 6) * 16;
#pragma unroll
    for (int i = 0; i < 16; i++) {
        int r = rb + i;
        t[r][c] = f2bf(src[(size_t)(y + r) * Dz + x + c]);
    }
    __syncthreads();
#pragma unroll
    for (int i = 0; i < 16; i++) {
        int r = rb + i;
        dst[(size_t)(x + r) * Dz + y + c] = t[c][r];
    }
}

// ---------------- GEMM: C = A[M,K](bf16) * Wt[N,K]^T(bf16), 128x128 tile ----
// MODE 0: fp32 row-major store to C (final output).
// MODE 1: bf16; z=0/1 scatter to [B,H,S,HD]; z=2 scatter to [B,H,HD,S].
template <int MODE>
__global__ void gemm_bt(const u16* __restrict__ A, const u16* __restrict__ BtBase,
                        void* __restrict__ CBase) {
    const int z = blockIdx.z;
    const u16* Bt = BtBase + (size_t)z * (Dz * Dz);
    const int tid = threadIdx.x, lane = tid & 63, wave = tid >> 6;
    const int ln = lane & 15, qd = lane >> 4;
    const int m0 = blockIdx.y * 128, n0 = blockIdx.x * 128;

    __shared__ __align__(16) u16 As[128][72];
    __shared__ __align__(16) u16 Bs[128][72];

    f32x4 acc[4][4];
#pragma unroll
    for (int i = 0; i < 4; i++)
#pragma unroll
        for (int j = 0; j < 4; j++) acc[i][j] = (f32x4){0.f, 0.f, 0.f, 0.f};

    const int wm = (wave >> 1) * 64, wn = (wave & 1) * 64;
    const int srow = tid >> 3, skv = (tid & 7) * 8;

    for (int k0 = 0; k0 < Dz; k0 += 64) {
#pragma unroll
        for (int i = 0; i < 4; i++) {
            int r = i * 32 + srow;
            *(uint4*)&As[r][skv] = *(const uint4*)(A  + (size_t)(m0 + r) * Dz + k0 + skv);
            *(uint4*)&Bs[r][skv] = *(const uint4*)(Bt + (size_t)(n0 + r) * Dz + k0 + skv);
        }
        __syncthreads();
#pragma unroll
        for (int kc = 0; kc < 2; kc++) {
            bf16x8 af[4], bff[4];
#pragma unroll
            for (int i = 0; i < 4; i++) {
                af[i]  = *(const bf16x8*)&As[wm + i * 16 + ln][kc * 32 + qd * 8];
                bff[i] = *(const bf16x8*)&Bs[wn + i * 16 + ln][kc * 32 + qd * 8];
            }
#pragma unroll
            for (int i = 0; i < 4; i++)
#pragma unroll
                for (int j = 0; j < 4; j++)
                    acc[i][j] = __builtin_amdgcn_mfma_f32_16x16x32_bf16(
                        af[i], bff[j], acc[i][j], 0, 0, 0);
        }
        __syncthreads();
    }

#pragma unroll
    for (int i = 0; i < 4; i++) {
#pragma unroll
        for (int j = 0; j < 4; j++) {
#pragma unroll
            for (int r = 0; r < 4; r++) {
                int row = m0 + wm + i * 16 + qd * 4 + r;
                int col = n0 + wn + j * 16 + ln;
                if (MODE == 0) {
                    ((float*)CBase)[(size_t)row * Dz + col] = acc[i][j][r];
                } else {
                    u16* C = (u16*)CBase + (size_t)z * ((size_t)Mz * Dz);
                    u16 hv = f2bf(acc[i][j][r]);
                    int bb = row >> 11, ss = row & 2047;
                    int hh = col >> 7, hd = col & 127;
                    if (z == 2)
                        C[((size_t)(bb * Hz + hh) * HDz + hd) * Sz + ss] = hv;
                    else
                        C[((size_t)(bb * Hz + hh) * Sz + ss) * HDz + hd] = hv;
                }
            }
        }
    }
}

// ---------------- RoPE in place on Q and K: [B,H,S,HD] (bf16) --------------
__global__ void rope_kernel(u16* __restrict__ Q, u16* __restrict__ Kk) {
    u32 idx = blockIdx.x * blockDim.x + threadIdx.x;   // 2^23 threads
    u16* T = (idx >> 22) ? Kk : Q;
    u32 p = idx & 0x3FFFFFu;                           // pair index within tensor
    int j = p & 63;
    int s = (p >> 6) & 2047;
    size_t base = (size_t)(p >> 6) * HDz + 2 * j;
    u32 u = *(u32*)(T + base);
    float x0 = bf2f((u16)(u & 0xFFFFu));
    float x1 = bf2f((u16)(u >> 16));
    int i0 = (2 * j) & 63;
    const float LG = 0.20762050593046017f;             // log2(10000)/64
    float f0 = exp2f(-LG * (float)i0);
    float f1 = exp2f(-LG * (float)(i0 + 1));
    float th0 = (float)s * f0, th1 = (float)s * f1;
    float s0, c0, s1, c1;
    sincosf(th0, &s0, &c0);
    sincosf(th1, &s1, &c1);
    float y0 = x0 * c0 - x1 * s0;                      // even: q*cos - q_odd*sin
    float y1 = x1 * c1 + x0 * s1;                      // odd:  q*cos + q_even*sin
    u32 outw = (u32)f2bf(y0) | ((u32)f2bf(y1) << 16);
    *(u32*)(T + base) = outw;
}

// ---------------- causal flash attention (bf16 in/out, fp32 softmax) -------
// Q,K: [B,H,S,HD]; Vt: [B,H,HD,S]; O: [B,S,H,HD]. 64 q-rows/block, 64-key tiles.
__global__ void flash_attn(const u16* __restrict__ Q, const u16* __restrict__ Kk,
                           const u16* __restrict__ Vt, u16* __restrict__ O) {
    const int tid = threadIdx.x, lane = tid & 63, wave = tid >> 6;
    const int ln = lane & 15, qd = lane >> 4;
    const int bh = blockIdx.x & 31;
    const int qt = 31 - (blockIdx.x >> 5);             // heavy q-tiles first
    const int b = bh >> 4, h = bh & 15;
    const int q0 = qt * 64;
    const u16* Qh = Q  + (size_t)bh * Sz * HDz;
    const u16* Kh = Kk + (size_t)bh * Sz * HDz;
    const u16* Vh = Vt + (size_t)bh * HDz * Sz;

    __shared__ __align__(16) u16 Qs[64][136];
    __shared__ __align__(16) u16 Ks[64][136];
    __shared__ __align__(16) u16 Vs[128][72];
    __shared__ __align__(16) u16 Ps[4][16][72];

    {
        int r = tid >> 4, cv = (tid & 15) * 8;
#pragma unroll
        for (int i = 0; i < 4; i++)
            *(uint4*)&Qs[i * 16 + r][cv] =
                *(const uint4*)(Qh + (size_t)(q0 + i * 16 + r) * HDz + cv);
    }
    __syncthreads();
    bf16x8 qf[4];
#pragma unroll
    for (int kc = 0; kc < 4; kc++)
        qf[kc] = *(const bf16x8*)&Qs[wave * 16 + ln][kc * 32 + qd * 8];

    float m_run[4], l_run[4];
    f32x4 oa[8];
#pragma unroll
    for (int r = 0; r < 4; r++) { m_run[r] = -INFINITY; l_run[r] = 0.f; }
#pragma unroll
    for (int n = 0; n < 8; n++) oa[n] = (f32x4){0.f, 0.f, 0.f, 0.f};

    const float SCALE = 0.08838834764831845f;          // 1/sqrt(128)

    for (int k0 = 0; k0 <= q0; k0 += 64) {
        {
            int r = tid >> 4, cv = (tid & 15) * 8;
#pragma unroll
            for (int i = 0; i < 4; i++)
                *(uint4*)&Ks[i * 16 + r][cv] =
                    *(const uint4*)(Kh + (size_t)(k0 + i * 16 + r) * HDz + cv);
            int hd = tid >> 3, kv = (tid & 7) * 8;
#pragma unroll
            for (int i = 0; i < 4; i++)
                *(uint4*)&Vs[i * 32 + hd][kv] =
                    *(const uint4*)(Vh + (size_t)(i * 32 + hd) * Sz + k0 + kv);
        }
        __syncthreads();

        // S = Q K^T  (M=16 q, N=64 keys per wave)
        f32x4 sc[4];
#pragma unroll
        for (int n = 0; n < 4; n++) sc[n] = (f32x4){0.f, 0.f, 0.f, 0.f};
#pragma unroll
        for (int kc = 0; kc < 4; kc++) {
#pragma unroll
            for (int n = 0; n < 4; n++) {
                bf16x8 kf = *(const bf16x8*)&Ks[n * 16 + ln][kc * 32 + qd * 8];
                sc[n] = __builtin_amdgcn_mfma_f32_16x16x32_bf16(qf[kc], kf, sc[n], 0, 0, 0);
            }
        }
#pragma unroll
        for (int n = 0; n < 4; n++)
#pragma unroll
            for (int r = 0; r < 4; r++) sc[n][r] *= SCALE;
        if (k0 == q0) {                                 // diagonal tile: causal mask
#pragma unroll
            for (int n = 0; n < 4; n++) {
                int key = n * 16 + ln;
#pragma unroll
                for (int r = 0; r < 4; r++) {
                    int qr = wave * 16 + qd * 4 + r;
                    if (key > qr) sc[n][r] = -1e30f;
                }
            }
        }

        // online softmax (rows live in 16-lane quad-groups)
        float pv[4][4];
#pragma unroll
        for (int r = 0; r < 4; r++) {
            float rm = fmaxf(fmaxf(sc[0][r], sc[1][r]), fmaxf(sc[2][r], sc[3][r]));
#pragma unroll
            for (int off = 8; off >= 1; off >>= 1) rm = fmaxf(rm, __shfl_xor(rm, off));
            float mn = fmaxf(m_run[r], rm);
            float al = __expf(m_run[r] - mn);           // first tile: exp(-inf)=0
            float sum = 0.f;
#pragma unroll
            for (int n = 0; n < 4; n++) {
                float p = __expf(sc[n][r] - mn);
                pv[n][r] = p;
                sum += p;
            }
#pragma unroll
            for (int off = 8; off >= 1; off >>= 1) sum += __shfl_xor(sum, off);
            m_run[r] = mn;
            l_run[r] = l_run[r] * al + sum;
#pragma unroll
            for (int n = 0; n < 8; n++) oa[n][r] *= al;
        }

        // P: D-layout -> A-layout via LDS
#pragma unroll
        for (int n = 0; n < 4; n++)
#pragma unroll
            for (int r = 0; r < 4; r++)
                Ps[wave][qd * 4 + r][n * 16 + ln] = f2bf(pv[n][r]);
        __syncthreads();

        // O += P V
#pragma unroll
        for (int kc = 0; kc < 2; kc++) {
            bf16x8 pf = *(const bf16x8*)&Ps[wave][ln][kc * 32 + qd * 8];
#pragma unroll
            for (int n = 0; n < 8; n++) {
                bf16x8 vf = *(const bf16x8*)&Vs[n * 16 + ln][kc * 32 + qd * 8];
                oa[n] = __builtin_amdgcn_mfma_f32_16x16x32_bf16(pf, vf, oa[n], 0, 0, 0);
            }
        }
        __syncthreads();
    }

#pragma unroll
    for (int r = 0; r < 4; r++) {
        int s = q0 + wave * 16 + qd * 4 + r;
        float inv = 1.0f / l_run[r];
        size_t base = ((size_t)b * Sz + s) * Dz + h * HDz;
#pragma unroll
        for (int n = 0; n < 8; n++)
            O[base + n * 16 + ln] = f2bf(oa[n][r] * inv);
    }
}

// ---------------------------------------------------------------------------
extern "C" void kernel_launch(void* const* d_in, const int* in_sizes, int n_in,
                              void* d_out, int out_size, void* d_ws, size_t ws_size,
                              hipStream_t stream) {
    const float* x  = (const float*)d_in[0];
    const float* Wq = (const float*)d_in[1];
    const float* Wk = (const float*)d_in[2];
    const float* Wv = (const float*)d_in[3];
    const float* Wo = (const float*)d_in[4];
    float* out = (float*)d_out;
    u16* ws  = (u16*)d_ws;

    // workspace layout (u16 elements):
    u16* wt = ws;                       // 4 * 4,194,304 transposed bf16 weights (32 MB)
    u16* q  = ws + 16777216;            // [B,H,S,HD]  8,388,608
    u16* kk = q + 8388608;              // [B,H,S,HD]  8,388,608
    u16* v  = kk + 8388608;             // [B,H,HD,S]  8,388,608
    u16* xb = v + 8388608;              // bf16(x) [B,S,D]; reused as o after gemm<1>
    u16* o  = xb;                       // flash output aliases xb (xb dead by then)

    cvt_f32_bf16<<<dim3(4096), 256, 0, stream>>>(x, xb);
    transpose_w<<<dim3(32, 32, 4), 256, 0, stream>>>(Wq, Wk, Wv, Wo, wt);
    gemm_bt<1><<<dim3(16, 32, 3), 256, 0, stream>>>(xb, wt, q);
    rope_kernel<<<dim3(32768), 256, 0, stream>>>(q, kk);
    flash_attn<<<dim3(1024), 256, 0, stream>>>(q, kk, v, o);
    gemm_bt<0><<<dim3(16, 32, 1), 256, 0, stream>>>(o, wt + 3 * 4194304, out);
}